// Round 4
// baseline (647.667 us; speedup 1.0000x reference)
//
#include <hip/hip_runtime.h>

#define NB    4096
#define SEQ   64
#define DIM   128
#define NHEAD 8
#define ATTD  32
#define HKC   256
#define SCALE 0.17677669529663687f

typedef __bf16 bf16_t;
typedef __bf16 bf16x8 __attribute__((ext_vector_type(8)));
typedef __bf16 bf16x4 __attribute__((ext_vector_type(4)));
typedef float  f32x4  __attribute__((ext_vector_type(4)));
typedef unsigned int u32;

static __device__ __forceinline__ bf16_t f2bf(float f) {
  unsigned u = __builtin_bit_cast(unsigned, f);
  u = (u + 0x7FFFu + ((u >> 16) & 1u)) >> 16;
  unsigned short s = (unsigned short)u;
  return __builtin_bit_cast(bf16_t, s);
}

// pack two f32 -> dword of 2 bf16 (lo=a, hi=b), RNE — pure bit math, no asm
static __device__ __forceinline__ u32 pkbf(float a, float b) {
  unsigned ua = __builtin_bit_cast(unsigned, a);
  ua = (ua + 0x7FFFu + ((ua >> 16) & 1u)) >> 16;
  unsigned ub = __builtin_bit_cast(unsigned, b);
  ub = (ub + 0x7FFFu + ((ub >> 16) & 1u)) & 0xFFFF0000u;
  return (ua & 0xFFFFu) | ub;
}

// D-layout -> MFMA A/B-frag merge, all-__shfl version (known-good from R3).
// Input: two 16x16 D-tiles t0 (X rows 0-15), t1 (rows 16-31); lane (g,lo)
// reg j = value (X = 4g+j, lo). Output: bf16x8 frag, lane (g,lo) elem e =
// value (X = 8g+e, lo). lo-dim untouched.
static __device__ __forceinline__ bf16x8 merge2(f32x4 t0, f32x4 t1, int lo, int g) {
  u32 p0 = pkbf(t0[0], t0[1]);
  u32 p1 = pkbf(t0[2], t0[3]);
  u32 q0 = pkbf(t1[0], t1[1]);
  u32 q1 = pkbf(t1[2], t1[3]);
  const int srcA = lo + ((g & 1) << 5);
  const int srcB = srcA + 16;
  u32 a0 = (u32)__shfl((int)p0, srcA, 64);
  u32 a1 = (u32)__shfl((int)p1, srcA, 64);
  u32 b0 = (u32)__shfl((int)p0, srcB, 64);
  u32 b1 = (u32)__shfl((int)p1, srcB, 64);
  u32 c0 = (u32)__shfl((int)q0, srcA, 64);
  u32 c1 = (u32)__shfl((int)q1, srcA, 64);
  u32 d0 = (u32)__shfl((int)q0, srcB, 64);
  u32 d1 = (u32)__shfl((int)q1, srcB, 64);
  const bool glow = (g < 2);
  union { u32 u[4]; bf16x8 v; } r;
  r.u[0] = glow ? a0 : c0;   // e=0,1 : X=8g+0,1
  r.u[1] = glow ? a1 : c1;   // e=2,3
  r.u[2] = glow ? b0 : d0;   // e=4,5
  r.u[3] = glow ? b1 : d1;   // e=6,7
  return r.v;
}

// ws layout (bf16): [0:32768) WqT[c][d] (pre-scaled by SCALE), [32768:65536) WkT,
// [65536:98304) WvT, [98304:131072) WresT; c = h*32+a (or res col), d = 0..127.
__global__ void prep_weights(const float* __restrict__ Wq,
                             const float* __restrict__ Wk,
                             const float* __restrict__ Wv,
                             const float* __restrict__ Wr,
                             bf16_t* __restrict__ ws) {
  int idx = blockIdx.x * 256 + threadIdx.x;  // 0..131071
  int m = idx >> 15;
  int e = idx & 32767;
  int c = e >> 7;
  int d = e & 127;
  float v;
  if (m == 0)      v = Wq[((c >> 5) * DIM + d) * ATTD + (c & 31)] * SCALE;
  else if (m == 1) v = Wk[((c >> 5) * DIM + d) * ATTD + (c & 31)];
  else if (m == 2) v = Wv[((c >> 5) * DIM + d) * ATTD + (c & 31)];
  else             v = Wr[d * HKC + c];
  ws[idx] = f2bf(v);
}

// One block per batch; 4 waves; wave w handles heads {2w,2w+1} = out cols [64w,64w+64).
// Only LDS: X tile. One barrier. Frag conversions via merge2 (register shuffles).
// Epilogue computes ctx^T / res^T so each lane holds 4 consecutive out cols -> float4.
__launch_bounds__(256, 6)
__global__ void fused_attn(const float* __restrict__ xg,
                           const bf16_t* __restrict__ ws,
                           float* __restrict__ outg) {
  __shared__ bf16_t Xb[64][136];  // pad 8 -> row 272B, 2-way-max bank aliasing (free)

  const int t  = threadIdx.x;
  const int w  = t >> 6;
  const int l  = t & 63;
  const int lo = l & 15;
  const int g  = l >> 4;
  const int b  = blockIdx.x;

  { // stage X -> LDS (bf16)
    const float* xb = xg + (size_t)b * (SEQ * DIM);
#pragma unroll
    for (int i = 0; i < 8; ++i) {
      int idx = i * 1024 + t * 4;
      float4 v = *(const float4*)(xb + idx);
      bf16x4 p;
      p[0] = f2bf(v.x); p[1] = f2bf(v.y); p[2] = f2bf(v.z); p[3] = f2bf(v.w);
      *(bf16x4*)&Xb[idx >> 7][idx & 127] = p;
    }
  }
  __syncthreads();

  const bf16_t* wsq = ws;
  const bf16_t* wsk = ws + 32768;
  const bf16_t* wsv = ws + 65536;
  const bf16_t* wsr = ws + 98304;
  float* ob = outg + (size_t)b * (SEQ * HKC);
  const f32x4 z4 = {0.f, 0.f, 0.f, 0.f};

#pragma unroll
  for (int hh = 0; hh < 2; ++hh) {
    const int hc = w * 64 + hh * 32;  // weight col base == output col base

    // ---- Q^T = (SCALE*Wq)^T X^T : tiles [at][mt], rows a, cols m ----
    f32x4 accq[2][4];
#pragma unroll
    for (int i = 0; i < 2; ++i)
#pragma unroll
      for (int j = 0; j < 4; ++j) accq[i][j] = z4;
#pragma unroll
    for (int kk = 0; kk < 4; ++kk) {
      bf16x8 aw[2], bx[4];
#pragma unroll
      for (int at = 0; at < 2; ++at)
        aw[at] = *(const bf16x8*)(wsq + (hc + at * 16 + lo) * DIM + kk * 32 + g * 8);
#pragma unroll
      for (int mt = 0; mt < 4; ++mt)
        bx[mt] = *(const bf16x8*)&Xb[mt * 16 + lo][kk * 32 + g * 8];
#pragma unroll
      for (int at = 0; at < 2; ++at)
#pragma unroll
        for (int mt = 0; mt < 4; ++mt)
          accq[at][mt] = __builtin_amdgcn_mfma_f32_16x16x32_bf16(aw[at], bx[mt], accq[at][mt], 0, 0, 0);
    }
    bf16x8 qf[4];  // B-frags for S^T: col m = lo, k = a = 8g+e
#pragma unroll
    for (int mt = 0; mt < 4; ++mt) qf[mt] = merge2(accq[0][mt], accq[1][mt], lo, g);

    // ---- K^T = Wk^T X^T : tiles [at][nt] ----
    f32x4 acck[2][4];
#pragma unroll
    for (int i = 0; i < 2; ++i)
#pragma unroll
      for (int j = 0; j < 4; ++j) acck[i][j] = z4;
#pragma unroll
    for (int kk = 0; kk < 4; ++kk) {
      bf16x8 aw[2], bx[4];
#pragma unroll
      for (int at = 0; at < 2; ++at)
        aw[at] = *(const bf16x8*)(wsk + (hc + at * 16 + lo) * DIM + kk * 32 + g * 8);
#pragma unroll
      for (int nt = 0; nt < 4; ++nt)
        bx[nt] = *(const bf16x8*)&Xb[nt * 16 + lo][kk * 32 + g * 8];
#pragma unroll
      for (int at = 0; at < 2; ++at)
#pragma unroll
        for (int nt = 0; nt < 4; ++nt)
          acck[at][nt] = __builtin_amdgcn_mfma_f32_16x16x32_bf16(aw[at], bx[nt], acck[at][nt], 0, 0, 0);
    }
    bf16x8 kf[4];  // A-frags for S^T: row n = lo, k = a = 8g+e
#pragma unroll
    for (int nt = 0; nt < 4; ++nt) kf[nt] = merge2(acck[0][nt], acck[1][nt], lo, g);

    // ---- S^T = K Q^T (per mt), softmax over n, P -> frags (k = n) ----
    bf16x8 pf[4][2];  // [mt][kk2]: outer idx m = lo, k = n = kk2*32 + 8g+e
#pragma unroll
    for (int mt = 0; mt < 4; ++mt) {
      f32x4 sv[4];
#pragma unroll
      for (int nt = 0; nt < 4; ++nt)
        sv[nt] = __builtin_amdgcn_mfma_f32_16x16x32_bf16(kf[nt], qf[mt], z4, 0, 0, 0);
      float mx = sv[0][0];
#pragma unroll
      for (int nt = 0; nt < 4; ++nt)
#pragma unroll
        for (int j = 0; j < 4; ++j) mx = fmaxf(mx, sv[nt][j]);
      mx = fmaxf(mx, __shfl_xor(mx, 16, 64));
      mx = fmaxf(mx, __shfl_xor(mx, 32, 64));
      float sum = 0.f;
#pragma unroll
      for (int nt = 0; nt < 4; ++nt)
#pragma unroll
        for (int j = 0; j < 4; ++j) {
          float e = __expf(sv[nt][j] - mx);
          sv[nt][j] = e;
          sum += e;
        }
      sum += __shfl_xor(sum, 16, 64);
      sum += __shfl_xor(sum, 32, 64);
      float rinv = __builtin_amdgcn_rcpf(sum);
#pragma unroll
      for (int nt = 0; nt < 4; ++nt) sv[nt] *= rinv;
      pf[mt][0] = merge2(sv[0], sv[1], lo, g);
      pf[mt][1] = merge2(sv[2], sv[3], lo, g);
    }

    // ---- V = X Wv : tiles [nt][ct], rows n(seq), cols c ----
    f32x4 accv[4][2];
#pragma unroll
    for (int i = 0; i < 4; ++i)
#pragma unroll
      for (int j = 0; j < 2; ++j) accv[i][j] = z4;
#pragma unroll
    for (int kk = 0; kk < 4; ++kk) {
      bf16x8 ax[4], bw[2];
#pragma unroll
      for (int nt = 0; nt < 4; ++nt)
        ax[nt] = *(const bf16x8*)&Xb[nt * 16 + lo][kk * 32 + g * 8];
#pragma unroll
      for (int ct = 0; ct < 2; ++ct)
        bw[ct] = *(const bf16x8*)(wsv + (hc + ct * 16 + lo) * DIM + kk * 32 + g * 8);
#pragma unroll
      for (int nt = 0; nt < 4; ++nt)
#pragma unroll
        for (int ct = 0; ct < 2; ++ct)
          accv[nt][ct] = __builtin_amdgcn_mfma_f32_16x16x32_bf16(ax[nt], bw[ct], accv[nt][ct], 0, 0, 0);
    }
    bf16x8 vf[2][2];  // [ct][kk2]: outer idx c = lo, k = n
#pragma unroll
    for (int ct = 0; ct < 2; ++ct) {
      vf[ct][0] = merge2(accv[0][ct], accv[1][ct], lo, g);
      vf[ct][1] = merge2(accv[2][ct], accv[3][ct], lo, g);
    }

    // ---- ctx^T = V^T P^T : tiles [ct][mt], rows c, cols m ----
    // vf as A-frag (row c = lo, k = n), pf as B-frag (col m = lo, k = n).
    f32x4 ch[2][4];
#pragma unroll
    for (int ct = 0; ct < 2; ++ct)
#pragma unroll
      for (int mt = 0; mt < 4; ++mt) {
        f32x4 a = __builtin_amdgcn_mfma_f32_16x16x32_bf16(vf[ct][0], pf[mt][0], z4, 0, 0, 0);
        ch[ct][mt] = __builtin_amdgcn_mfma_f32_16x16x32_bf16(vf[ct][1], pf[mt][1], a, 0, 0, 0);
      }

    // ---- ctx^T += Wres^T X^T (this head's 32 cols) ----
#pragma unroll
    for (int kk = 0; kk < 4; ++kk) {
      bf16x8 aw[2], bx[4];
#pragma unroll
      for (int ct = 0; ct < 2; ++ct)
        aw[ct] = *(const bf16x8*)(wsr + (hc + ct * 16 + lo) * DIM + kk * 32 + g * 8);
#pragma unroll
      for (int mt = 0; mt < 4; ++mt)
        bx[mt] = *(const bf16x8*)&Xb[mt * 16 + lo][kk * 32 + g * 8];
#pragma unroll
      for (int ct = 0; ct < 2; ++ct)
#pragma unroll
        for (int mt = 0; mt < 4; ++mt)
          ch[ct][mt] = __builtin_amdgcn_mfma_f32_16x16x32_bf16(aw[ct], bx[mt], ch[ct][mt], 0, 0, 0);
    }

    // ---- ReLU + float4 store: lane (g,lo), tile (ct,mt) ->
    //      rows c = hc+ct*16+4g+j (j=0..3 contiguous), col m = mt*16+lo ----
#pragma unroll
    for (int ct = 0; ct < 2; ++ct)
#pragma unroll
      for (int mt = 0; mt < 4; ++mt) {
        float4 o;
        o.x = fmaxf(ch[ct][mt][0], 0.f);
        o.y = fmaxf(ch[ct][mt][1], 0.f);
        o.z = fmaxf(ch[ct][mt][2], 0.f);
        o.w = fmaxf(ch[ct][mt][3], 0.f);
        *(float4*)(ob + (mt * 16 + lo) * HKC + hc + ct * 16 + 4 * g) = o;
      }
  }
}

extern "C" void kernel_launch(void* const* d_in, const int* in_sizes, int n_in,
                              void* d_out, int out_size, void* d_ws, size_t ws_size,
                              hipStream_t stream) {
  const float* x  = (const float*)d_in[0];
  const float* Wq = (const float*)d_in[1];
  const float* Wk = (const float*)d_in[2];
  const float* Wv = (const float*)d_in[3];
  const float* Wr = (const float*)d_in[4];
  bf16_t* ws = (bf16_t*)d_ws;
  float* out = (float*)d_out;

  prep_weights<<<512, 256, 0, stream>>>(Wq, Wk, Wv, Wr, ws);
  fused_attn<<<NB, 256, 0, stream>>>(x, ws, out);
}

// Round 5
// 414.196 us; speedup vs baseline: 1.5637x; 1.5637x over previous
//
#include <hip/hip_runtime.h>

#define NB    4096
#define SEQ   64
#define DIM   128
#define NHEAD 8
#define ATTD  32
#define HKC   256
#define SCALE 0.17677669529663687f

typedef __bf16 bf16_t;
typedef __bf16 bf16x8 __attribute__((ext_vector_type(8)));
typedef __bf16 bf16x4 __attribute__((ext_vector_type(4)));
typedef float  f32x4  __attribute__((ext_vector_type(4)));
typedef unsigned int u32;

static __device__ __forceinline__ bf16_t f2bf(float f) {
  unsigned u = __builtin_bit_cast(unsigned, f);
  u = (u + 0x7FFFu + ((u >> 16) & 1u)) >> 16;
  unsigned short s = (unsigned short)u;
  return __builtin_bit_cast(bf16_t, s);
}

// pack two f32 -> dword of 2 bf16 (lo=a, hi=b), RNE — pure bit math, no asm
static __device__ __forceinline__ u32 pkbf(float a, float b) {
  unsigned ua = __builtin_bit_cast(unsigned, a);
  ua = (ua + 0x7FFFu + ((ua >> 16) & 1u)) >> 16;
  unsigned ub = __builtin_bit_cast(unsigned, b);
  ub = (ub + 0x7FFFu + ((ub >> 16) & 1u)) & 0xFFFF0000u;
  return (ua & 0xFFFFu) | ub;
}

// D-layout -> MFMA A/B-frag merge, all-__shfl version (known-good from R3).
// Input: two 16x16 D-tiles t0 (X rows 0-15), t1 (rows 16-31); lane (g,lo)
// reg j = value (X = 4g+j, lo). Output: bf16x8 frag, lane (g,lo) elem e =
// value (X = 8g+e, lo). lo-dim untouched.
static __device__ __forceinline__ bf16x8 merge2(f32x4 t0, f32x4 t1, int lo, int g) {
  u32 p0 = pkbf(t0[0], t0[1]);
  u32 p1 = pkbf(t0[2], t0[3]);
  u32 q0 = pkbf(t1[0], t1[1]);
  u32 q1 = pkbf(t1[2], t1[3]);
  const int srcA = lo + ((g & 1) << 5);
  const int srcB = srcA + 16;
  u32 a0 = (u32)__shfl((int)p0, srcA, 64);
  u32 a1 = (u32)__shfl((int)p1, srcA, 64);
  u32 b0 = (u32)__shfl((int)p0, srcB, 64);
  u32 b1 = (u32)__shfl((int)p1, srcB, 64);
  u32 c0 = (u32)__shfl((int)q0, srcA, 64);
  u32 c1 = (u32)__shfl((int)q1, srcA, 64);
  u32 d0 = (u32)__shfl((int)q0, srcB, 64);
  u32 d1 = (u32)__shfl((int)q1, srcB, 64);
  const bool glow = (g < 2);
  union { u32 u[4]; bf16x8 v; } r;
  r.u[0] = glow ? a0 : c0;   // e=0,1 : X=8g+0,1
  r.u[1] = glow ? a1 : c1;   // e=2,3
  r.u[2] = glow ? b0 : d0;   // e=4,5
  r.u[3] = glow ? b1 : d1;   // e=6,7
  return r.v;
}

// ws layout (bf16): [0:32768) WqT[c][d] (pre-scaled by SCALE), [32768:65536) WkT,
// [65536:98304) WvT, [98304:131072) WresT; c = h*32+a (or res col), d = 0..127.
__global__ void prep_weights(const float* __restrict__ Wq,
                             const float* __restrict__ Wk,
                             const float* __restrict__ Wv,
                             const float* __restrict__ Wr,
                             bf16_t* __restrict__ ws) {
  int idx = blockIdx.x * 256 + threadIdx.x;  // 0..131071
  int m = idx >> 15;
  int e = idx & 32767;
  int c = e >> 7;
  int d = e & 127;
  float v;
  if (m == 0)      v = Wq[((c >> 5) * DIM + d) * ATTD + (c & 31)] * SCALE;
  else if (m == 1) v = Wk[((c >> 5) * DIM + d) * ATTD + (c & 31)];
  else if (m == 2) v = Wv[((c >> 5) * DIM + d) * ATTD + (c & 31)];
  else             v = Wr[d * HKC + c];
  ws[idx] = f2bf(v);
}

// One block per batch; 4 waves; wave w handles heads {2w,2w+1} = out cols [64w,64w+64).
// Only LDS: X tile. One barrier. Frag conversions via merge2 (register shuffles).
// Epilogue computes ctx^T / res^T so each lane holds 4 consecutive out cols -> float4.
__launch_bounds__(256, 4)
__global__ void fused_attn(const float* __restrict__ xg,
                           const bf16_t* __restrict__ ws,
                           float* __restrict__ outg) {
  __shared__ bf16_t Xb[64][136];  // pad 8 -> row 272B, 2-way-max bank aliasing (free)

  const int t  = threadIdx.x;
  const int w  = t >> 6;
  const int l  = t & 63;
  const int lo = l & 15;
  const int g  = l >> 4;
  const int b  = blockIdx.x;

  { // stage X -> LDS (bf16)
    const float* xb = xg + (size_t)b * (SEQ * DIM);
#pragma unroll
    for (int i = 0; i < 8; ++i) {
      int idx = i * 1024 + t * 4;
      float4 v = *(const float4*)(xb + idx);
      bf16x4 p;
      p[0] = f2bf(v.x); p[1] = f2bf(v.y); p[2] = f2bf(v.z); p[3] = f2bf(v.w);
      *(bf16x4*)&Xb[idx >> 7][idx & 127] = p;
    }
  }
  __syncthreads();

  const bf16_t* wsq = ws;
  const bf16_t* wsk = ws + 32768;
  const bf16_t* wsv = ws + 65536;
  const bf16_t* wsr = ws + 98304;
  float* ob = outg + (size_t)b * (SEQ * HKC);
  const f32x4 z4 = {0.f, 0.f, 0.f, 0.f};

#pragma unroll
  for (int hh = 0; hh < 2; ++hh) {
    const int hc = w * 64 + hh * 32;  // weight col base == output col base

    // ---- Q^T = (SCALE*Wq)^T X^T : tiles [at][mt], rows a, cols m ----
    f32x4 accq[2][4];
#pragma unroll
    for (int i = 0; i < 2; ++i)
#pragma unroll
      for (int j = 0; j < 4; ++j) accq[i][j] = z4;
#pragma unroll
    for (int kk = 0; kk < 4; ++kk) {
      bf16x8 aw[2], bx[4];
#pragma unroll
      for (int at = 0; at < 2; ++at)
        aw[at] = *(const bf16x8*)(wsq + (hc + at * 16 + lo) * DIM + kk * 32 + g * 8);
#pragma unroll
      for (int mt = 0; mt < 4; ++mt)
        bx[mt] = *(const bf16x8*)&Xb[mt * 16 + lo][kk * 32 + g * 8];
#pragma unroll
      for (int at = 0; at < 2; ++at)
#pragma unroll
        for (int mt = 0; mt < 4; ++mt)
          accq[at][mt] = __builtin_amdgcn_mfma_f32_16x16x32_bf16(aw[at], bx[mt], accq[at][mt], 0, 0, 0);
    }
    bf16x8 qf[4];  // B-frags for S^T: col m = lo, k = a = 8g+e
#pragma unroll
    for (int mt = 0; mt < 4; ++mt) qf[mt] = merge2(accq[0][mt], accq[1][mt], lo, g);

    // ---- K^T = Wk^T X^T : tiles [at][nt] ----
    f32x4 acck[2][4];
#pragma unroll
    for (int i = 0; i < 2; ++i)
#pragma unroll
      for (int j = 0; j < 4; ++j) acck[i][j] = z4;
#pragma unroll
    for (int kk = 0; kk < 4; ++kk) {
      bf16x8 aw[2], bx[4];
#pragma unroll
      for (int at = 0; at < 2; ++at)
        aw[at] = *(const bf16x8*)(wsk + (hc + at * 16 + lo) * DIM + kk * 32 + g * 8);
#pragma unroll
      for (int nt = 0; nt < 4; ++nt)
        bx[nt] = *(const bf16x8*)&Xb[nt * 16 + lo][kk * 32 + g * 8];
#pragma unroll
      for (int at = 0; at < 2; ++at)
#pragma unroll
        for (int nt = 0; nt < 4; ++nt)
          acck[at][nt] = __builtin_amdgcn_mfma_f32_16x16x32_bf16(aw[at], bx[nt], acck[at][nt], 0, 0, 0);
    }
    bf16x8 kf[4];  // A-frags for S^T: row n = lo, k = a = 8g+e
#pragma unroll
    for (int nt = 0; nt < 4; ++nt) kf[nt] = merge2(acck[0][nt], acck[1][nt], lo, g);

    // ---- S^T = K Q^T (per mt), softmax over n, P -> frags (k = n) ----
    bf16x8 pf[4][2];  // [mt][kk2]: outer idx m = lo, k = n = kk2*32 + 8g+e
#pragma unroll
    for (int mt = 0; mt < 4; ++mt) {
      f32x4 sv[4];
#pragma unroll
      for (int nt = 0; nt < 4; ++nt)
        sv[nt] = __builtin_amdgcn_mfma_f32_16x16x32_bf16(kf[nt], qf[mt], z4, 0, 0, 0);
      float mx = sv[0][0];
#pragma unroll
      for (int nt = 0; nt < 4; ++nt)
#pragma unroll
        for (int j = 0; j < 4; ++j) mx = fmaxf(mx, sv[nt][j]);
      mx = fmaxf(mx, __shfl_xor(mx, 16, 64));
      mx = fmaxf(mx, __shfl_xor(mx, 32, 64));
      float sum = 0.f;
#pragma unroll
      for (int nt = 0; nt < 4; ++nt)
#pragma unroll
        for (int j = 0; j < 4; ++j) {
          float e = __expf(sv[nt][j] - mx);
          sv[nt][j] = e;
          sum += e;
        }
      sum += __shfl_xor(sum, 16, 64);
      sum += __shfl_xor(sum, 32, 64);
      float rinv = __builtin_amdgcn_rcpf(sum);
#pragma unroll
      for (int nt = 0; nt < 4; ++nt) sv[nt] *= rinv;
      pf[mt][0] = merge2(sv[0], sv[1], lo, g);
      pf[mt][1] = merge2(sv[2], sv[3], lo, g);
    }

    // ---- V = X Wv : tiles [nt][ct], rows n(seq), cols c ----
    f32x4 accv[4][2];
#pragma unroll
    for (int i = 0; i < 4; ++i)
#pragma unroll
      for (int j = 0; j < 2; ++j) accv[i][j] = z4;
#pragma unroll
    for (int kk = 0; kk < 4; ++kk) {
      bf16x8 ax[4], bw[2];
#pragma unroll
      for (int nt = 0; nt < 4; ++nt)
        ax[nt] = *(const bf16x8*)&Xb[nt * 16 + lo][kk * 32 + g * 8];
#pragma unroll
      for (int ct = 0; ct < 2; ++ct)
        bw[ct] = *(const bf16x8*)(wsv + (hc + ct * 16 + lo) * DIM + kk * 32 + g * 8);
#pragma unroll
      for (int nt = 0; nt < 4; ++nt)
#pragma unroll
        for (int ct = 0; ct < 2; ++ct)
          accv[nt][ct] = __builtin_amdgcn_mfma_f32_16x16x32_bf16(ax[nt], bw[ct], accv[nt][ct], 0, 0, 0);
    }
    bf16x8 vf[2][2];  // [ct][kk2]: outer idx c = lo, k = n
#pragma unroll
    for (int ct = 0; ct < 2; ++ct) {
      vf[ct][0] = merge2(accv[0][ct], accv[1][ct], lo, g);
      vf[ct][1] = merge2(accv[2][ct], accv[3][ct], lo, g);
    }

    // ---- ctx^T = V^T P^T : tiles [ct][mt], rows c, cols m ----
    // vf as A-frag (row c = lo, k = n), pf as B-frag (col m = lo, k = n).
    f32x4 ch[2][4];
#pragma unroll
    for (int ct = 0; ct < 2; ++ct)
#pragma unroll
      for (int mt = 0; mt < 4; ++mt) {
        f32x4 a = __builtin_amdgcn_mfma_f32_16x16x32_bf16(vf[ct][0], pf[mt][0], z4, 0, 0, 0);
        ch[ct][mt] = __builtin_amdgcn_mfma_f32_16x16x32_bf16(vf[ct][1], pf[mt][1], a, 0, 0, 0);
      }

    // ---- ctx^T += Wres^T X^T (this head's 32 cols) ----
#pragma unroll
    for (int kk = 0; kk < 4; ++kk) {
      bf16x8 aw[2], bx[4];
#pragma unroll
      for (int ct = 0; ct < 2; ++ct)
        aw[ct] = *(const bf16x8*)(wsr + (hc + ct * 16 + lo) * DIM + kk * 32 + g * 8);
#pragma unroll
      for (int mt = 0; mt < 4; ++mt)
        bx[mt] = *(const bf16x8*)&Xb[mt * 16 + lo][kk * 32 + g * 8];
#pragma unroll
      for (int ct = 0; ct < 2; ++ct)
#pragma unroll
        for (int mt = 0; mt < 4; ++mt)
          ch[ct][mt] = __builtin_amdgcn_mfma_f32_16x16x32_bf16(aw[ct], bx[mt], ch[ct][mt], 0, 0, 0);
    }

    // ---- ReLU + float4 store: lane (g,lo), tile (ct,mt) ->
    //      rows c = hc+ct*16+4g+j (j=0..3 contiguous), col m = mt*16+lo ----
#pragma unroll
    for (int ct = 0; ct < 2; ++ct)
#pragma unroll
      for (int mt = 0; mt < 4; ++mt) {
        float4 o;
        o.x = fmaxf(ch[ct][mt][0], 0.f);
        o.y = fmaxf(ch[ct][mt][1], 0.f);
        o.z = fmaxf(ch[ct][mt][2], 0.f);
        o.w = fmaxf(ch[ct][mt][3], 0.f);
        *(float4*)(ob + (mt * 16 + lo) * HKC + hc + ct * 16 + 4 * g) = o;
      }
  }
}

extern "C" void kernel_launch(void* const* d_in, const int* in_sizes, int n_in,
                              void* d_out, int out_size, void* d_ws, size_t ws_size,
                              hipStream_t stream) {
  const float* x  = (const float*)d_in[0];
  const float* Wq = (const float*)d_in[1];
  const float* Wk = (const float*)d_in[2];
  const float* Wv = (const float*)d_in[3];
  const float* Wr = (const float*)d_in[4];
  bf16_t* ws = (bf16_t*)d_ws;
  float* out = (float*)d_out;

  prep_weights<<<512, 256, 0, stream>>>(Wq, Wk, Wv, Wr, ws);
  fused_attn<<<NB, 256, 0, stream>>>(x, ws, out);
}

// Round 6
// 208.490 us; speedup vs baseline: 3.1065x; 1.9867x over previous
//
#include <hip/hip_runtime.h>

#define NB    4096
#define SEQ   64
#define DIM   128
#define NHEAD 8
#define ATTD  32
#define HKC   256
#define SCALE 0.17677669529663687f

typedef __bf16 bf16_t;
typedef __bf16 bf16x8 __attribute__((ext_vector_type(8)));
typedef __bf16 bf16x4 __attribute__((ext_vector_type(4)));
typedef float  f32x4  __attribute__((ext_vector_type(4)));
typedef unsigned int u32;

static __device__ __forceinline__ bf16_t f2bf(float f) {
  unsigned u = __builtin_bit_cast(unsigned, f);
  u = (u + 0x7FFFu + ((u >> 16) & 1u)) >> 16;
  unsigned short s = (unsigned short)u;
  return __builtin_bit_cast(bf16_t, s);
}

// pack two f32 -> dword of 2 bf16 (lo=a, hi=b), RNE — pure bit math, no asm
static __device__ __forceinline__ u32 pkbf(float a, float b) {
  unsigned ua = __builtin_bit_cast(unsigned, a);
  ua = (ua + 0x7FFFu + ((ua >> 16) & 1u)) >> 16;
  unsigned ub = __builtin_bit_cast(unsigned, b);
  ub = (ub + 0x7FFFu + ((ub >> 16) & 1u)) & 0xFFFF0000u;
  return (ua & 0xFFFFu) | ub;
}

// D-layout -> MFMA A/B-frag merge, all-__shfl version (known-good from R3).
// Input: two 16x16 D-tiles t0 (X rows 0-15), t1 (rows 16-31); lane (g,lo)
// reg j = value (X = 4g+j, lo). Output: bf16x8 frag, lane (g,lo) elem e =
// value (X = 8g+e, lo). lo-dim untouched.
static __device__ __forceinline__ bf16x8 merge2(f32x4 t0, f32x4 t1, int lo, int g) {
  u32 p0 = pkbf(t0[0], t0[1]);
  u32 p1 = pkbf(t0[2], t0[3]);
  u32 q0 = pkbf(t1[0], t1[1]);
  u32 q1 = pkbf(t1[2], t1[3]);
  const int srcA = lo + ((g & 1) << 5);
  const int srcB = srcA + 16;
  u32 a0 = (u32)__shfl((int)p0, srcA, 64);
  u32 a1 = (u32)__shfl((int)p1, srcA, 64);
  u32 b0 = (u32)__shfl((int)p0, srcB, 64);
  u32 b1 = (u32)__shfl((int)p1, srcB, 64);
  u32 c0 = (u32)__shfl((int)q0, srcA, 64);
  u32 c1 = (u32)__shfl((int)q1, srcA, 64);
  u32 d0 = (u32)__shfl((int)q0, srcB, 64);
  u32 d1 = (u32)__shfl((int)q1, srcB, 64);
  const bool glow = (g < 2);
  union { u32 u[4]; bf16x8 v; } r;
  r.u[0] = glow ? a0 : c0;   // e=0,1 : X=8g+0,1
  r.u[1] = glow ? a1 : c1;   // e=2,3
  r.u[2] = glow ? b0 : d0;   // e=4,5
  r.u[3] = glow ? b1 : d1;   // e=6,7
  return r.v;
}

// ws layout (bf16): [0:32768) WqT[c][d] (pre-scaled by SCALE), [32768:65536) WkT,
// [65536:98304) WvT, [98304:131072) WresT; c = h*32+a (or res col), d = 0..127.
__global__ void prep_weights(const float* __restrict__ Wq,
                             const float* __restrict__ Wk,
                             const float* __restrict__ Wv,
                             const float* __restrict__ Wr,
                             bf16_t* __restrict__ ws) {
  int idx = blockIdx.x * 256 + threadIdx.x;  // 0..131071
  int m = idx >> 15;
  int e = idx & 32767;
  int c = e >> 7;
  int d = e & 127;
  float v;
  if (m == 0)      v = Wq[((c >> 5) * DIM + d) * ATTD + (c & 31)] * SCALE;
  else if (m == 1) v = Wk[((c >> 5) * DIM + d) * ATTD + (c & 31)];
  else if (m == 2) v = Wv[((c >> 5) * DIM + d) * ATTD + (c & 31)];
  else             v = Wr[d * HKC + c];
  ws[idx] = f2bf(v);
}

// One block per batch; 4 waves; wave w handles heads {2w,2w+1}.
// LDS: X tile (block-shared, one barrier) + per-wave V^T and P^T transpose
// buffers (wave-private -> no barriers, in-order DS ops).
// Q,K frag conversion: merge2 (register shuffles). V,P: LDS b64-write/b128-read.
// Epilogue: ctx^T/res^T so each lane holds 4 consecutive out cols -> float4.
__launch_bounds__(256, 3)
__global__ void fused_attn(const float* __restrict__ xg,
                           const bf16_t* __restrict__ ws,
                           float* __restrict__ outg) {
  __shared__ bf16_t Xb[64][136];      // pad: row 272B
  __shared__ bf16_t Vt[4][32][72];    // per-wave V^T[c][n], row 144B (16B-mult)
  __shared__ bf16_t Pt[4][16][72];    // per-wave P^T-slice [m-local][n]

  const int t  = threadIdx.x;
  const int w  = t >> 6;
  const int l  = t & 63;
  const int lo = l & 15;
  const int g  = l >> 4;
  const int b  = blockIdx.x;

  { // stage X -> LDS (bf16)
    const float* xb = xg + (size_t)b * (SEQ * DIM);
#pragma unroll
    for (int i = 0; i < 8; ++i) {
      int idx = i * 1024 + t * 4;
      float4 v = *(const float4*)(xb + idx);
      bf16x4 p;
      p[0] = f2bf(v.x); p[1] = f2bf(v.y); p[2] = f2bf(v.z); p[3] = f2bf(v.w);
      *(bf16x4*)&Xb[idx >> 7][idx & 127] = p;
    }
  }
  __syncthreads();

  const bf16_t* wsq = ws;
  const bf16_t* wsk = ws + 32768;
  const bf16_t* wsv = ws + 65536;
  const bf16_t* wsr = ws + 98304;
  float* ob = outg + (size_t)b * (SEQ * HKC);
  const f32x4 z4 = {0.f, 0.f, 0.f, 0.f};

#pragma unroll
  for (int hh = 0; hh < 2; ++hh) {
    const int hc = w * 64 + hh * 32;  // weight col base == output col base

    // ---- K^T = Wk^T X^T : tiles [at][nt], rows a, cols n ----
    f32x4 acck[2][4];
#pragma unroll
    for (int i = 0; i < 2; ++i)
#pragma unroll
      for (int j = 0; j < 4; ++j) acck[i][j] = z4;
#pragma unroll
    for (int kk = 0; kk < 4; ++kk) {
      bf16x8 aw[2], bx[4];
#pragma unroll
      for (int at = 0; at < 2; ++at)
        aw[at] = *(const bf16x8*)(wsk + (hc + at * 16 + lo) * DIM + kk * 32 + g * 8);
#pragma unroll
      for (int nt = 0; nt < 4; ++nt)
        bx[nt] = *(const bf16x8*)&Xb[nt * 16 + lo][kk * 32 + g * 8];
#pragma unroll
      for (int at = 0; at < 2; ++at)
#pragma unroll
        for (int nt = 0; nt < 4; ++nt)
          acck[at][nt] = __builtin_amdgcn_mfma_f32_16x16x32_bf16(aw[at], bx[nt], acck[at][nt], 0, 0, 0);
    }
    bf16x8 kf[4];  // A-frags for S^T: row n = lo, k = a = 8g+e
#pragma unroll
    for (int nt = 0; nt < 4; ++nt) kf[nt] = merge2(acck[0][nt], acck[1][nt], lo, g);

    // ---- V = X Wv : tiles [nt][ct], rows n(seq) = nt*16+4g+j, cols c = lo ----
    // write V^T to LDS: Vt[c][n], b64 per tile
    f32x4 accv[4][2];
#pragma unroll
    for (int i = 0; i < 4; ++i)
#pragma unroll
      for (int j = 0; j < 2; ++j) accv[i][j] = z4;
#pragma unroll
    for (int kk = 0; kk < 4; ++kk) {
      bf16x8 ax[4], bw[2];
#pragma unroll
      for (int nt = 0; nt < 4; ++nt)
        ax[nt] = *(const bf16x8*)&Xb[nt * 16 + lo][kk * 32 + g * 8];
#pragma unroll
      for (int ct = 0; ct < 2; ++ct)
        bw[ct] = *(const bf16x8*)(wsv + (hc + ct * 16 + lo) * DIM + kk * 32 + g * 8);
#pragma unroll
      for (int nt = 0; nt < 4; ++nt)
#pragma unroll
        for (int ct = 0; ct < 2; ++ct)
          accv[nt][ct] = __builtin_amdgcn_mfma_f32_16x16x32_bf16(ax[nt], bw[ct], accv[nt][ct], 0, 0, 0);
    }
#pragma unroll
    for (int nt = 0; nt < 4; ++nt)
#pragma unroll
      for (int ct = 0; ct < 2; ++ct) {
        uint2 d;
        d.x = pkbf(accv[nt][ct][0], accv[nt][ct][1]);
        d.y = pkbf(accv[nt][ct][2], accv[nt][ct][3]);
        *(uint2*)&Vt[w][ct * 16 + lo][nt * 16 + 4 * g] = d;
      }

    // ---- Q^T = (SCALE*Wq)^T X^T : tiles [at][mt], rows a, cols m ----
    f32x4 accq[2][4];
#pragma unroll
    for (int i = 0; i < 2; ++i)
#pragma unroll
      for (int j = 0; j < 4; ++j) accq[i][j] = z4;
#pragma unroll
    for (int kk = 0; kk < 4; ++kk) {
      bf16x8 aw[2], bx[4];
#pragma unroll
      for (int at = 0; at < 2; ++at)
        aw[at] = *(const bf16x8*)(wsq + (hc + at * 16 + lo) * DIM + kk * 32 + g * 8);
#pragma unroll
      for (int mt = 0; mt < 4; ++mt)
        bx[mt] = *(const bf16x8*)&Xb[mt * 16 + lo][kk * 32 + g * 8];
#pragma unroll
      for (int at = 0; at < 2; ++at)
#pragma unroll
        for (int mt = 0; mt < 4; ++mt)
          accq[at][mt] = __builtin_amdgcn_mfma_f32_16x16x32_bf16(aw[at], bx[mt], accq[at][mt], 0, 0, 0);
    }
    bf16x8 qf[4];  // B-frags for S^T: col m = lo, k = a = 8g+e
#pragma unroll
    for (int mt = 0; mt < 4; ++mt) qf[mt] = merge2(accq[0][mt], accq[1][mt], lo, g);

    // ---- load vf B-frags from LDS: col c = lo, k = n = kk2*32+8g+e ----
    bf16x8 vf[2][2];
#pragma unroll
    for (int ct = 0; ct < 2; ++ct)
#pragma unroll
      for (int kk2 = 0; kk2 < 2; ++kk2)
        vf[ct][kk2] = *(const bf16x8*)&Vt[w][ct * 16 + lo][kk2 * 32 + g * 8];

    // ---- per mt: S^T = K Q^T, softmax over n, P^T via LDS, PV ----
    f32x4 ch[2][4];  // [ct][mt]: rows c = 4g+j, cols m = lo
#pragma unroll
    for (int mt = 0; mt < 4; ++mt) {
      f32x4 sv[4];
#pragma unroll
      for (int nt = 0; nt < 4; ++nt)
        sv[nt] = __builtin_amdgcn_mfma_f32_16x16x32_bf16(kf[nt], qf[mt], z4, 0, 0, 0);
      float mx = sv[0][0];
#pragma unroll
      for (int nt = 0; nt < 4; ++nt)
#pragma unroll
        for (int j = 0; j < 4; ++j) mx = fmaxf(mx, sv[nt][j]);
      mx = fmaxf(mx, __shfl_xor(mx, 16, 64));
      mx = fmaxf(mx, __shfl_xor(mx, 32, 64));
      float sum = 0.f;
#pragma unroll
      for (int nt = 0; nt < 4; ++nt)
#pragma unroll
        for (int j = 0; j < 4; ++j) {
          float e = __expf(sv[nt][j] - mx);
          sv[nt][j] = e;
          sum += e;
        }
      sum += __shfl_xor(sum, 16, 64);
      sum += __shfl_xor(sum, 32, 64);
      float rinv = __builtin_amdgcn_rcpf(sum);
#pragma unroll
      for (int nt = 0; nt < 4; ++nt) sv[nt] *= rinv;
      // write P^T slice: lane holds (n = nt*16+4g+j, m-local = lo)
#pragma unroll
      for (int nt = 0; nt < 4; ++nt) {
        uint2 d;
        d.x = pkbf(sv[nt][0], sv[nt][1]);
        d.y = pkbf(sv[nt][2], sv[nt][3]);
        *(uint2*)&Pt[w][lo][nt * 16 + 4 * g] = d;
      }
      // read back as B-frags (col m = lo, k = n) and do PV
      bf16x8 pf0 = *(const bf16x8*)&Pt[w][lo][g * 8];
      bf16x8 pf1 = *(const bf16x8*)&Pt[w][lo][32 + g * 8];
#pragma unroll
      for (int ct = 0; ct < 2; ++ct) {
        f32x4 a = __builtin_amdgcn_mfma_f32_16x16x32_bf16(vf[ct][0], pf0, z4, 0, 0, 0);
        ch[ct][mt] = __builtin_amdgcn_mfma_f32_16x16x32_bf16(vf[ct][1], pf1, a, 0, 0, 0);
      }
    }

    // ---- ctx^T += Wres^T X^T (this head's 32 cols) ----
#pragma unroll
    for (int kk = 0; kk < 4; ++kk) {
      bf16x8 aw[2], bx[4];
#pragma unroll
      for (int ct = 0; ct < 2; ++ct)
        aw[ct] = *(const bf16x8*)(wsr + (hc + ct * 16 + lo) * DIM + kk * 32 + g * 8);
#pragma unroll
      for (int mt = 0; mt < 4; ++mt)
        bx[mt] = *(const bf16x8*)&Xb[mt * 16 + lo][kk * 32 + g * 8];
#pragma unroll
      for (int ct = 0; ct < 2; ++ct)
#pragma unroll
        for (int mt = 0; mt < 4; ++mt)
          ch[ct][mt] = __builtin_amdgcn_mfma_f32_16x16x32_bf16(aw[ct], bx[mt], ch[ct][mt], 0, 0, 0);
    }

    // ---- ReLU + float4 store: rows c = hc+ct*16+4g+j, col m = mt*16+lo ----
#pragma unroll
    for (int ct = 0; ct < 2; ++ct)
#pragma unroll
      for (int mt = 0; mt < 4; ++mt) {
        float4 o;
        o.x = fmaxf(ch[ct][mt][0], 0.f);
        o.y = fmaxf(ch[ct][mt][1], 0.f);
        o.z = fmaxf(ch[ct][mt][2], 0.f);
        o.w = fmaxf(ch[ct][mt][3], 0.f);
        *(float4*)(ob + (mt * 16 + lo) * HKC + hc + ct * 16 + 4 * g) = o;
      }
  }
}

extern "C" void kernel_launch(void* const* d_in, const int* in_sizes, int n_in,
                              void* d_out, int out_size, void* d_ws, size_t ws_size,
                              hipStream_t stream) {
  const float* x  = (const float*)d_in[0];
  const float* Wq = (const float*)d_in[1];
  const float* Wk = (const float*)d_in[2];
  const float* Wv = (const float*)d_in[3];
  const float* Wr = (const float*)d_in[4];
  bf16_t* ws = (bf16_t*)d_ws;
  float* out = (float*)d_out;

  prep_weights<<<512, 256, 0, stream>>>(Wq, Wk, Wv, Wr, ws);
  fused_attn<<<NB, 256, 0, stream>>>(x, ws, out);
}

// Round 7
// 203.775 us; speedup vs baseline: 3.1783x; 1.0231x over previous
//
#include <hip/hip_runtime.h>

#define NB    4096
#define SEQ   64
#define DIM   128
#define NHEAD 8
#define ATTD  32
#define HKC   256
#define SCALE 0.17677669529663687f
#define LOG2E 1.4426950408889634f

typedef __bf16 bf16_t;
typedef __bf16 bf16x8 __attribute__((ext_vector_type(8)));
typedef __bf16 bf16x4 __attribute__((ext_vector_type(4)));
typedef float  f32x4  __attribute__((ext_vector_type(4)));
typedef unsigned int u32;

static __device__ __forceinline__ bf16_t f2bf(float f) {
  unsigned u = __builtin_bit_cast(unsigned, f);
  u = (u + 0x7FFFu + ((u >> 16) & 1u)) >> 16;
  unsigned short s = (unsigned short)u;
  return __builtin_bit_cast(bf16_t, s);
}

// pack two f32 -> dword of 2 bf16 (lo=a, hi=b), RNE — pure bit math, no asm
static __device__ __forceinline__ u32 pkbf(float a, float b) {
  unsigned ua = __builtin_bit_cast(unsigned, a);
  ua = (ua + 0x7FFFu + ((ua >> 16) & 1u)) >> 16;
  unsigned ub = __builtin_bit_cast(unsigned, b);
  ub = (ub + 0x7FFFu + ((ub >> 16) & 1u)) & 0xFFFF0000u;
  return (ua & 0xFFFFu) | ub;
}

// D-layout -> MFMA A/B-frag merge, all-__shfl version (known-good from R3).
static __device__ __forceinline__ bf16x8 merge2(f32x4 t0, f32x4 t1, int lo, int g) {
  u32 p0 = pkbf(t0[0], t0[1]);
  u32 p1 = pkbf(t0[2], t0[3]);
  u32 q0 = pkbf(t1[0], t1[1]);
  u32 q1 = pkbf(t1[2], t1[3]);
  const int srcA = lo + ((g & 1) << 5);
  const int srcB = srcA + 16;
  u32 a0 = (u32)__shfl((int)p0, srcA, 64);
  u32 a1 = (u32)__shfl((int)p1, srcA, 64);
  u32 b0 = (u32)__shfl((int)p0, srcB, 64);
  u32 b1 = (u32)__shfl((int)p1, srcB, 64);
  u32 c0 = (u32)__shfl((int)q0, srcA, 64);
  u32 c1 = (u32)__shfl((int)q1, srcA, 64);
  u32 d0 = (u32)__shfl((int)q0, srcB, 64);
  u32 d1 = (u32)__shfl((int)q1, srcB, 64);
  const bool glow = (g < 2);
  union { u32 u[4]; bf16x8 v; } r;
  r.u[0] = glow ? a0 : c0;
  r.u[1] = glow ? a1 : c1;
  r.u[2] = glow ? b0 : d0;
  r.u[3] = glow ? b1 : d1;
  return r.v;
}

// XOR swizzle: element index within an unpadded row; XOR bits >=3 only, so any
// 8-element (16B) block stays contiguous and 4-elem (8B) writes stay aligned.
#define XSWZ(r, c) (((r) << 7) + ((c) ^ (((r) & 7) << 3)))   // Xb: 64x128
#define VSWZ(r, c) (((r) << 6) + ((c) ^ (((r) & 7) << 3)))   // Vt: 32x64
#define PSWZ(r, c) (((r) << 6) + ((c) ^ (((r) & 7) << 3)))   // Pt: 16x64

// ws layout (bf16): [0:32768) WqT[c][d] (pre-scaled by SCALE*log2e),
// [32768:65536) WkT, [65536:98304) WvT, [98304:131072) WresT.
__global__ void prep_weights(const float* __restrict__ Wq,
                             const float* __restrict__ Wk,
                             const float* __restrict__ Wv,
                             const float* __restrict__ Wr,
                             bf16_t* __restrict__ ws) {
  int idx = blockIdx.x * 256 + threadIdx.x;  // 0..131071
  int m = idx >> 15;
  int e = idx & 32767;
  int c = e >> 7;
  int d = e & 127;
  float v;
  if (m == 0)      v = Wq[((c >> 5) * DIM + d) * ATTD + (c & 31)] * (SCALE * LOG2E);
  else if (m == 1) v = Wk[((c >> 5) * DIM + d) * ATTD + (c & 31)];
  else if (m == 2) v = Wv[((c >> 5) * DIM + d) * ATTD + (c & 31)];
  else             v = Wr[d * HKC + c];
  ws[idx] = f2bf(v);
}

// One block per batch; 4 waves; wave w handles heads {2w,2w+1}.
// LDS (40960 B exactly -> 4 blocks/CU): swizzled X tile + per-wave V^T/P^T.
// Softmax: no max-subtract (exp2 of pre-scaled scores), normalization deferred
// to the ctx accumulator (per-lane scalar), sum reduce off the critical path.
__launch_bounds__(256, 3)
__global__ void fused_attn(const float* __restrict__ xg,
                           const bf16_t* __restrict__ ws,
                           float* __restrict__ outg) {
  __shared__ bf16_t Xb[64 * 128];
  __shared__ bf16_t Vt[4][32 * 64];
  __shared__ bf16_t Pt[4][16 * 64];

  const int t  = threadIdx.x;
  const int w  = t >> 6;
  const int l  = t & 63;
  const int lo = l & 15;
  const int g  = l >> 4;
  const int b  = blockIdx.x;

  { // stage X -> LDS (bf16, swizzled)
    const float* xb = xg + (size_t)b * (SEQ * DIM);
#pragma unroll
    for (int i = 0; i < 8; ++i) {
      int idx = i * 1024 + t * 4;
      float4 v = *(const float4*)(xb + idx);
      bf16x4 p;
      p[0] = f2bf(v.x); p[1] = f2bf(v.y); p[2] = f2bf(v.z); p[3] = f2bf(v.w);
      *(bf16x4*)&Xb[XSWZ(idx >> 7, idx & 127)] = p;
    }
  }
  __syncthreads();

  const bf16_t* wsq = ws;
  const bf16_t* wsk = ws + 32768;
  const bf16_t* wsv = ws + 65536;
  const bf16_t* wsr = ws + 98304;
  float* ob = outg + (size_t)b * (SEQ * HKC);
  const f32x4 z4 = {0.f, 0.f, 0.f, 0.f};

#pragma unroll
  for (int hh = 0; hh < 2; ++hh) {
    const int hc = w * 64 + hh * 32;  // weight col base == output col base

    // ---- K^T = Wk^T X^T : tiles [at][nt], rows a, cols n ----
    f32x4 acck[2][4];
#pragma unroll
    for (int i = 0; i < 2; ++i)
#pragma unroll
      for (int j = 0; j < 4; ++j) acck[i][j] = z4;
#pragma unroll
    for (int kk = 0; kk < 4; ++kk) {
      bf16x8 aw[2], bx[4];
#pragma unroll
      for (int at = 0; at < 2; ++at)
        aw[at] = *(const bf16x8*)(wsk + (hc + at * 16 + lo) * DIM + kk * 32 + g * 8);
#pragma unroll
      for (int nt = 0; nt < 4; ++nt)
        bx[nt] = *(const bf16x8*)&Xb[XSWZ(nt * 16 + lo, kk * 32 + g * 8)];
#pragma unroll
      for (int at = 0; at < 2; ++at)
#pragma unroll
        for (int nt = 0; nt < 4; ++nt)
          acck[at][nt] = __builtin_amdgcn_mfma_f32_16x16x32_bf16(aw[at], bx[nt], acck[at][nt], 0, 0, 0);
    }
    bf16x8 kf[4];  // A-frags for S^T: row n = lo, k = a = 8g+e
#pragma unroll
    for (int nt = 0; nt < 4; ++nt) kf[nt] = merge2(acck[0][nt], acck[1][nt], lo, g);

    // ---- V = X Wv : tiles [nt][ct]; write V^T to LDS (swizzled) ----
    f32x4 accv[4][2];
#pragma unroll
    for (int i = 0; i < 4; ++i)
#pragma unroll
      for (int j = 0; j < 2; ++j) accv[i][j] = z4;
#pragma unroll
    for (int kk = 0; kk < 4; ++kk) {
      bf16x8 ax[4], bw[2];
#pragma unroll
      for (int nt = 0; nt < 4; ++nt)
        ax[nt] = *(const bf16x8*)&Xb[XSWZ(nt * 16 + lo, kk * 32 + g * 8)];
#pragma unroll
      for (int ct = 0; ct < 2; ++ct)
        bw[ct] = *(const bf16x8*)(wsv + (hc + ct * 16 + lo) * DIM + kk * 32 + g * 8);
#pragma unroll
      for (int nt = 0; nt < 4; ++nt)
#pragma unroll
        for (int ct = 0; ct < 2; ++ct)
          accv[nt][ct] = __builtin_amdgcn_mfma_f32_16x16x32_bf16(ax[nt], bw[ct], accv[nt][ct], 0, 0, 0);
    }
#pragma unroll
    for (int nt = 0; nt < 4; ++nt)
#pragma unroll
      for (int ct = 0; ct < 2; ++ct) {
        uint2 d;
        d.x = pkbf(accv[nt][ct][0], accv[nt][ct][1]);
        d.y = pkbf(accv[nt][ct][2], accv[nt][ct][3]);
        *(uint2*)&Vt[w][VSWZ(ct * 16 + lo, nt * 16 + 4 * g)] = d;
      }

    // ---- Q^T = (SCALE*log2e*Wq)^T X^T : tiles [at][mt] ----
    f32x4 accq[2][4];
#pragma unroll
    for (int i = 0; i < 2; ++i)
#pragma unroll
      for (int j = 0; j < 4; ++j) accq[i][j] = z4;
#pragma unroll
    for (int kk = 0; kk < 4; ++kk) {
      bf16x8 aw[2], bx[4];
#pragma unroll
      for (int at = 0; at < 2; ++at)
        aw[at] = *(const bf16x8*)(wsq + (hc + at * 16 + lo) * DIM + kk * 32 + g * 8);
#pragma unroll
      for (int mt = 0; mt < 4; ++mt)
        bx[mt] = *(const bf16x8*)&Xb[XSWZ(mt * 16 + lo, kk * 32 + g * 8)];
#pragma unroll
      for (int at = 0; at < 2; ++at)
#pragma unroll
        for (int mt = 0; mt < 4; ++mt)
          accq[at][mt] = __builtin_amdgcn_mfma_f32_16x16x32_bf16(aw[at], bx[mt], accq[at][mt], 0, 0, 0);
    }
    bf16x8 qf[4];  // B-frags for S^T: col m = lo, k = a = 8g+e
#pragma unroll
    for (int mt = 0; mt < 4; ++mt) qf[mt] = merge2(accq[0][mt], accq[1][mt], lo, g);

    // ---- load vf B-frags from LDS: col c = lo, k = n = kk2*32+8g+e ----
    bf16x8 vf[2][2];
#pragma unroll
    for (int ct = 0; ct < 2; ++ct)
#pragma unroll
      for (int kk2 = 0; kk2 < 2; ++kk2)
        vf[ct][kk2] = *(const bf16x8*)&Vt[w][VSWZ(ct * 16 + lo, kk2 * 32 + g * 8)];

    // ---- per mt: S^T (log2-domain), exp2, P^T via LDS, PV, deferred norm ----
    f32x4 ch[2][4];  // [ct][mt]: rows c = 4g+j, cols m = lo
#pragma unroll
    for (int mt = 0; mt < 4; ++mt) {
      f32x4 sv[4];
#pragma unroll
      for (int nt = 0; nt < 4; ++nt)
        sv[nt] = __builtin_amdgcn_mfma_f32_16x16x32_bf16(kf[nt], qf[mt], z4, 0, 0, 0);
      // E = 2^S (scores pre-scaled by log2e); no max-subtract (range-safe)
      float sum = 0.f;
#pragma unroll
      for (int nt = 0; nt < 4; ++nt)
#pragma unroll
        for (int j = 0; j < 4; ++j) {
          float e = __builtin_amdgcn_exp2f(sv[nt][j]);
          sv[nt][j] = e;
          sum += e;
        }
      // write unnormalized P^T slice ASAP (lane holds n = nt*16+4g+j, m = lo)
#pragma unroll
      for (int nt = 0; nt < 4; ++nt) {
        uint2 d;
        d.x = pkbf(sv[nt][0], sv[nt][1]);
        d.y = pkbf(sv[nt][2], sv[nt][3]);
        *(uint2*)&Pt[w][PSWZ(lo, nt * 16 + 4 * g)] = d;
      }
      // sum reduce off the P path (overlaps with LDS drain)
      sum += __shfl_xor(sum, 16, 64);
      sum += __shfl_xor(sum, 32, 64);
      float rinv = __builtin_amdgcn_rcpf(sum);
      // read back as B-frags (col m = lo, k = n) and do PV
      bf16x8 pf0 = *(const bf16x8*)&Pt[w][PSWZ(lo, g * 8)];
      bf16x8 pf1 = *(const bf16x8*)&Pt[w][PSWZ(lo, 32 + g * 8)];
#pragma unroll
      for (int ct = 0; ct < 2; ++ct) {
        f32x4 a = __builtin_amdgcn_mfma_f32_16x16x32_bf16(vf[ct][0], pf0, z4, 0, 0, 0);
        a = __builtin_amdgcn_mfma_f32_16x16x32_bf16(vf[ct][1], pf1, a, 0, 0, 0);
        ch[ct][mt] = a * rinv;  // deferred softmax normalization (m = lo)
      }
    }

    // ---- ctx^T += Wres^T X^T (this head's 32 cols) ----
#pragma unroll
    for (int kk = 0; kk < 4; ++kk) {
      bf16x8 aw[2], bx[4];
#pragma unroll
      for (int ct = 0; ct < 2; ++ct)
        aw[ct] = *(const bf16x8*)(wsr + (hc + ct * 16 + lo) * DIM + kk * 32 + g * 8);
#pragma unroll
      for (int mt = 0; mt < 4; ++mt)
        bx[mt] = *(const bf16x8*)&Xb[XSWZ(mt * 16 + lo, kk * 32 + g * 8)];
#pragma unroll
      for (int ct = 0; ct < 2; ++ct)
#pragma unroll
        for (int mt = 0; mt < 4; ++mt)
          ch[ct][mt] = __builtin_amdgcn_mfma_f32_16x16x32_bf16(aw[ct], bx[mt], ch[ct][mt], 0, 0, 0);
    }

    // ---- ReLU + float4 store: rows c = hc+ct*16+4g+j, col m = mt*16+lo ----
#pragma unroll
    for (int ct = 0; ct < 2; ++ct)
#pragma unroll
      for (int mt = 0; mt < 4; ++mt) {
        float4 o;
        o.x = fmaxf(ch[ct][mt][0], 0.f);
        o.y = fmaxf(ch[ct][mt][1], 0.f);
        o.z = fmaxf(ch[ct][mt][2], 0.f);
        o.w = fmaxf(ch[ct][mt][3], 0.f);
        *(float4*)(ob + (mt * 16 + lo) * HKC + hc + ct * 16 + 4 * g) = o;
      }
  }
}

extern "C" void kernel_launch(void* const* d_in, const int* in_sizes, int n_in,
                              void* d_out, int out_size, void* d_ws, size_t ws_size,
                              hipStream_t stream) {
  const float* x  = (const float*)d_in[0];
  const float* Wq = (const float*)d_in[1];
  const float* Wk = (const float*)d_in[2];
  const float* Wv = (const float*)d_in[3];
  const float* Wr = (const float*)d_in[4];
  bf16_t* ws = (bf16_t*)d_ws;
  float* out = (float*)d_out;

  prep_weights<<<512, 256, 0, stream>>>(Wq, Wk, Wv, Wr, ws);
  fused_attn<<<NB, 256, 0, stream>>>(x, ws, out);
}

// Round 8
// 200.869 us; speedup vs baseline: 3.2243x; 1.0145x over previous
//
#include <hip/hip_runtime.h>

#define NB    4096
#define SEQ   64
#define DIM   128
#define NHEAD 8
#define ATTD  32
#define HKC   256
#define SCALE 0.17677669529663687f
#define LOG2E 1.4426950408889634f

typedef __bf16 bf16_t;
typedef __bf16 bf16x8 __attribute__((ext_vector_type(8)));
typedef __bf16 bf16x4 __attribute__((ext_vector_type(4)));
typedef float  f32x4  __attribute__((ext_vector_type(4)));
typedef unsigned int u32;

static __device__ __forceinline__ bf16_t f2bf(float f) {
  unsigned u = __builtin_bit_cast(unsigned, f);
  u = (u + 0x7FFFu + ((u >> 16) & 1u)) >> 16;
  unsigned short s = (unsigned short)u;
  return __builtin_bit_cast(bf16_t, s);
}

// pack two f32 -> dword of 2 bf16 (lo=a, hi=b), RNE — pure bit math, no asm
static __device__ __forceinline__ u32 pkbf(float a, float b) {
  unsigned ua = __builtin_bit_cast(unsigned, a);
  ua = (ua + 0x7FFFu + ((ua >> 16) & 1u)) >> 16;
  unsigned ub = __builtin_bit_cast(unsigned, b);
  ub = (ub + 0x7FFFu + ((ub >> 16) & 1u)) & 0xFFFF0000u;
  return (ua & 0xFFFFu) | ub;
}

// D-layout -> MFMA A/B-frag merge, all-__shfl version (known-good from R3).
static __device__ __forceinline__ bf16x8 merge2(f32x4 t0, f32x4 t1, int lo, int g) {
  u32 p0 = pkbf(t0[0], t0[1]);
  u32 p1 = pkbf(t0[2], t0[3]);
  u32 q0 = pkbf(t1[0], t1[1]);
  u32 q1 = pkbf(t1[2], t1[3]);
  const int srcA = lo + ((g & 1) << 5);
  const int srcB = srcA + 16;
  u32 a0 = (u32)__shfl((int)p0, srcA, 64);
  u32 a1 = (u32)__shfl((int)p1, srcA, 64);
  u32 b0 = (u32)__shfl((int)p0, srcB, 64);
  u32 b1 = (u32)__shfl((int)p1, srcB, 64);
  u32 c0 = (u32)__shfl((int)q0, srcA, 64);
  u32 c1 = (u32)__shfl((int)q1, srcA, 64);
  u32 d0 = (u32)__shfl((int)q0, srcB, 64);
  u32 d1 = (u32)__shfl((int)q1, srcB, 64);
  const bool glow = (g < 2);
  union { u32 u[4]; bf16x8 v; } r;
  r.u[0] = glow ? a0 : c0;
  r.u[1] = glow ? a1 : c1;
  r.u[2] = glow ? b0 : d0;
  r.u[3] = glow ? b1 : d1;
  return r.v;
}

// XOR swizzle: element index within an unpadded row; XOR bits >=3 only, so any
// 8-element (16B) block stays contiguous and 4-elem (8B) writes stay aligned.
#define XSWZ(r, c) (((r) << 7) + ((c) ^ (((r) & 7) << 3)))   // Xb: 64x128
#define VSWZ(r, c) (((r) << 6) + ((c) ^ (((r) & 7) << 3)))   // Vt: 32x64
#define PSWZ(r, c) (((r) << 6) + ((c) ^ (((r) & 7) << 3)))   // Pt: 16x64

// ws layout (bf16): [0:32768) WqT[c][d] (pre-scaled by SCALE*log2e),
// [32768:65536) WkT, [65536:98304) WvT, [98304:131072) WresT.
__global__ void prep_weights(const float* __restrict__ Wq,
                             const float* __restrict__ Wk,
                             const float* __restrict__ Wv,
                             const float* __restrict__ Wr,
                             bf16_t* __restrict__ ws) {
  int idx = blockIdx.x * 256 + threadIdx.x;  // 0..131071
  int m = idx >> 15;
  int e = idx & 32767;
  int c = e >> 7;
  int d = e & 127;
  float v;
  if (m == 0)      v = Wq[((c >> 5) * DIM + d) * ATTD + (c & 31)] * (SCALE * LOG2E);
  else if (m == 1) v = Wk[((c >> 5) * DIM + d) * ATTD + (c & 31)];
  else if (m == 2) v = Wv[((c >> 5) * DIM + d) * ATTD + (c & 31)];
  else             v = Wr[d * HKC + c];
  ws[idx] = f2bf(v);
}

// One block per batch; 4 waves; wave w handles heads {2w,2w+1}.
// LDS = 32768 B total (-> 4-5 blocks/CU): swizzled X tile + ONE 4 KB per-wave
// scratch, time-shared: V^T (written then read into regs) then P^T (per mt).
// Aliasing is wave-private with in-order DS ops -> safe; compiler sees the
// same base pointer, so WAR ordering is preserved.
__launch_bounds__(256, 3)
__global__ void fused_attn(const float* __restrict__ xg,
                           const bf16_t* __restrict__ ws,
                           float* __restrict__ outg) {
  __shared__ bf16_t Xb[64 * 128];
  __shared__ bf16_t VP[4][32 * 64];   // per-wave scratch: Vt, then Pt (alias)

  const int t  = threadIdx.x;
  const int w  = t >> 6;
  const int l  = t & 63;
  const int lo = l & 15;
  const int g  = l >> 4;
  const int b  = blockIdx.x;

  bf16_t* const vtw = VP[w];
  bf16_t* const ptw = VP[w];   // alias: Pt lives in Vt's space after vf load

  { // stage X -> LDS (bf16, swizzled)
    const float* xb = xg + (size_t)b * (SEQ * DIM);
#pragma unroll
    for (int i = 0; i < 8; ++i) {
      int idx = i * 1024 + t * 4;
      float4 v = *(const float4*)(xb + idx);
      bf16x4 p;
      p[0] = f2bf(v.x); p[1] = f2bf(v.y); p[2] = f2bf(v.z); p[3] = f2bf(v.w);
      *(bf16x4*)&Xb[XSWZ(idx >> 7, idx & 127)] = p;
    }
  }
  __syncthreads();

  const bf16_t* wsq = ws;
  const bf16_t* wsk = ws + 32768;
  const bf16_t* wsv = ws + 65536;
  const bf16_t* wsr = ws + 98304;
  float* ob = outg + (size_t)b * (SEQ * HKC);
  const f32x4 z4 = {0.f, 0.f, 0.f, 0.f};

#pragma unroll
  for (int hh = 0; hh < 2; ++hh) {
    const int hc = w * 64 + hh * 32;  // weight col base == output col base

    // ---- K^T = Wk^T X^T : tiles [at][nt], rows a, cols n ----
    f32x4 acck[2][4];
#pragma unroll
    for (int i = 0; i < 2; ++i)
#pragma unroll
      for (int j = 0; j < 4; ++j) acck[i][j] = z4;
#pragma unroll
    for (int kk = 0; kk < 4; ++kk) {
      bf16x8 aw[2], bx[4];
#pragma unroll
      for (int at = 0; at < 2; ++at)
        aw[at] = *(const bf16x8*)(wsk + (hc + at * 16 + lo) * DIM + kk * 32 + g * 8);
#pragma unroll
      for (int nt = 0; nt < 4; ++nt)
        bx[nt] = *(const bf16x8*)&Xb[XSWZ(nt * 16 + lo, kk * 32 + g * 8)];
#pragma unroll
      for (int at = 0; at < 2; ++at)
#pragma unroll
        for (int nt = 0; nt < 4; ++nt)
          acck[at][nt] = __builtin_amdgcn_mfma_f32_16x16x32_bf16(aw[at], bx[nt], acck[at][nt], 0, 0, 0);
    }
    bf16x8 kf[4];  // A-frags for S^T: row n = lo, k = a = 8g+e
#pragma unroll
    for (int nt = 0; nt < 4; ++nt) kf[nt] = merge2(acck[0][nt], acck[1][nt], lo, g);

    // ---- V = X Wv : tiles [nt][ct]; write V^T to LDS (swizzled) ----
    f32x4 accv[4][2];
#pragma unroll
    for (int i = 0; i < 4; ++i)
#pragma unroll
      for (int j = 0; j < 2; ++j) accv[i][j] = z4;
#pragma unroll
    for (int kk = 0; kk < 4; ++kk) {
      bf16x8 ax[4], bw[2];
#pragma unroll
      for (int nt = 0; nt < 4; ++nt)
        ax[nt] = *(const bf16x8*)&Xb[XSWZ(nt * 16 + lo, kk * 32 + g * 8)];
#pragma unroll
      for (int ct = 0; ct < 2; ++ct)
        bw[ct] = *(const bf16x8*)(wsv + (hc + ct * 16 + lo) * DIM + kk * 32 + g * 8);
#pragma unroll
      for (int nt = 0; nt < 4; ++nt)
#pragma unroll
        for (int ct = 0; ct < 2; ++ct)
          accv[nt][ct] = __builtin_amdgcn_mfma_f32_16x16x32_bf16(ax[nt], bw[ct], accv[nt][ct], 0, 0, 0);
    }
#pragma unroll
    for (int nt = 0; nt < 4; ++nt)
#pragma unroll
      for (int ct = 0; ct < 2; ++ct) {
        uint2 d;
        d.x = pkbf(accv[nt][ct][0], accv[nt][ct][1]);
        d.y = pkbf(accv[nt][ct][2], accv[nt][ct][3]);
        *(uint2*)&vtw[VSWZ(ct * 16 + lo, nt * 16 + 4 * g)] = d;
      }

    // ---- Q^T = (SCALE*log2e*Wq)^T X^T : tiles [at][mt] ----
    f32x4 accq[2][4];
#pragma unroll
    for (int i = 0; i < 2; ++i)
#pragma unroll
      for (int j = 0; j < 4; ++j) accq[i][j] = z4;
#pragma unroll
    for (int kk = 0; kk < 4; ++kk) {
      bf16x8 aw[2], bx[4];
#pragma unroll
      for (int at = 0; at < 2; ++at)
        aw[at] = *(const bf16x8*)(wsq + (hc + at * 16 + lo) * DIM + kk * 32 + g * 8);
#pragma unroll
      for (int mt = 0; mt < 4; ++mt)
        bx[mt] = *(const bf16x8*)&Xb[XSWZ(mt * 16 + lo, kk * 32 + g * 8)];
#pragma unroll
      for (int at = 0; at < 2; ++at)
#pragma unroll
        for (int mt = 0; mt < 4; ++mt)
          accq[at][mt] = __builtin_amdgcn_mfma_f32_16x16x32_bf16(aw[at], bx[mt], accq[at][mt], 0, 0, 0);
    }
    bf16x8 qf[4];  // B-frags for S^T: col m = lo, k = a = 8g+e
#pragma unroll
    for (int mt = 0; mt < 4; ++mt) qf[mt] = merge2(accq[0][mt], accq[1][mt], lo, g);

    // ---- load vf B-frags from LDS: col c = lo, k = n = kk2*32+8g+e ----
    bf16x8 vf[2][2];
#pragma unroll
    for (int ct = 0; ct < 2; ++ct)
#pragma unroll
      for (int kk2 = 0; kk2 < 2; ++kk2)
        vf[ct][kk2] = *(const bf16x8*)&vtw[VSWZ(ct * 16 + lo, kk2 * 32 + g * 8)];

    // ---- per mt: S^T (log2-domain), exp2, P^T via LDS (aliases Vt), PV ----
    f32x4 ch[2][4];  // [ct][mt]: rows c = 4g+j, cols m = lo
#pragma unroll
    for (int mt = 0; mt < 4; ++mt) {
      f32x4 sv[4];
#pragma unroll
      for (int nt = 0; nt < 4; ++nt)
        sv[nt] = __builtin_amdgcn_mfma_f32_16x16x32_bf16(kf[nt], qf[mt], z4, 0, 0, 0);
      // E = 2^S (scores pre-scaled by log2e); no max-subtract (range-safe)
      float sum = 0.f;
#pragma unroll
      for (int nt = 0; nt < 4; ++nt)
#pragma unroll
        for (int j = 0; j < 4; ++j) {
          float e = __builtin_amdgcn_exp2f(sv[nt][j]);
          sv[nt][j] = e;
          sum += e;
        }
      // write unnormalized P^T slice ASAP (lane holds n = nt*16+4g+j, m = lo)
#pragma unroll
      for (int nt = 0; nt < 4; ++nt) {
        uint2 d;
        d.x = pkbf(sv[nt][0], sv[nt][1]);
        d.y = pkbf(sv[nt][2], sv[nt][3]);
        *(uint2*)&ptw[PSWZ(lo, nt * 16 + 4 * g)] = d;
      }
      // sum reduce off the P path (overlaps with LDS drain)
      sum += __shfl_xor(sum, 16, 64);
      sum += __shfl_xor(sum, 32, 64);
      float rinv = __builtin_amdgcn_rcpf(sum);
      // read back as B-frags (col m = lo, k = n) and do PV
      bf16x8 pf0 = *(const bf16x8*)&ptw[PSWZ(lo, g * 8)];
      bf16x8 pf1 = *(const bf16x8*)&ptw[PSWZ(lo, 32 + g * 8)];
#pragma unroll
      for (int ct = 0; ct < 2; ++ct) {
        f32x4 a = __builtin_amdgcn_mfma_f32_16x16x32_bf16(vf[ct][0], pf0, z4, 0, 0, 0);
        a = __builtin_amdgcn_mfma_f32_16x16x32_bf16(vf[ct][1], pf1, a, 0, 0, 0);
        ch[ct][mt] = a * rinv;  // deferred softmax normalization (m = lo)
      }
    }

    // ---- ctx^T += Wres^T X^T (this head's 32 cols) ----
#pragma unroll
    for (int kk = 0; kk < 4; ++kk) {
      bf16x8 aw[2], bx[4];
#pragma unroll
      for (int ct = 0; ct < 2; ++ct)
        aw[ct] = *(const bf16x8*)(wsr + (hc + ct * 16 + lo) * DIM + kk * 32 + g * 8);
#pragma unroll
      for (int mt = 0; mt < 4; ++mt)
        bx[mt] = *(const bf16x8*)&Xb[XSWZ(mt * 16 + lo, kk * 32 + g * 8)];
#pragma unroll
      for (int ct = 0; ct < 2; ++ct)
#pragma unroll
        for (int mt = 0; mt < 4; ++mt)
          ch[ct][mt] = __builtin_amdgcn_mfma_f32_16x16x32_bf16(aw[ct], bx[mt], ch[ct][mt], 0, 0, 0);
    }

    // ---- ReLU + float4 store: rows c = hc+ct*16+4g+j, col m = mt*16+lo ----
#pragma unroll
    for (int ct = 0; ct < 2; ++ct)
#pragma unroll
      for (int mt = 0; mt < 4; ++mt) {
        float4 o;
        o.x = fmaxf(ch[ct][mt][0], 0.f);
        o.y = fmaxf(ch[ct][mt][1], 0.f);
        o.z = fmaxf(ch[ct][mt][2], 0.f);
        o.w = fmaxf(ch[ct][mt][3], 0.f);
        *(float4*)(ob + (mt * 16 + lo) * HKC + hc + ct * 16 + 4 * g) = o;
      }
  }
}

extern "C" void kernel_launch(void* const* d_in, const int* in_sizes, int n_in,
                              void* d_out, int out_size, void* d_ws, size_t ws_size,
                              hipStream_t stream) {
  const float* x  = (const float*)d_in[0];
  const float* Wq = (const float*)d_in[1];
  const float* Wk = (const float*)d_in[2];
  const float* Wv = (const float*)d_in[3];
  const float* Wr = (const float*)d_in[4];
  bf16_t* ws = (bf16_t*)d_ws;
  float* out = (float*)d_out;

  prep_weights<<<512, 256, 0, stream>>>(Wq, Wk, Wv, Wr, ws);
  fused_attn<<<NB, 256, 0, stream>>>(x, ws, out);
}